// Round 1
// 712.615 us; speedup vs baseline: 1.4357x; 1.4357x over previous
//
#include <hip/hip_runtime.h>
#include <hip/hip_fp16.h>
#include <cstdint>
#include <cstddef>

#define B_   4
#define T_   4096
#define D_   2560
#define H_   10
#define BW   256
#define NROWS (B_*T_)   // 16384
#define CCH  32         // number of chunks along T
#define LCH  128        // chunk length (CCH*LCH == T_)

typedef short s16x8 __attribute__((ext_vector_type(8)));
typedef float f32x4 __attribute__((ext_vector_type(4)));

__device__ __forceinline__ unsigned short f2bf(float f) {
  union { float f; uint32_t u; } v; v.f = f;
  uint32_t u = v.u;
  u += 0x7fffu + ((u >> 16) & 1u);   // round-to-nearest-even
  return (unsigned short)(u >> 16);
}

// ---------------- prep: transpose+cast weights to bf16 [H][512][256] (n-major,
// k-contiguous, n<256 = ig cols, n>=256 = rg cols), and softplus(recurrent_param)
__global__ __launch_bounds__(256) void prep_kernel(
    const float* __restrict__ igw, const float* __restrict__ rgw,
    const float* __restrict__ rp,
    unsigned short* __restrict__ wt, float* __restrict__ sp) {
  int idx = blockIdx.x * 256 + threadIdx.x;
  const int total = H_ * 512 * 256;
  if (idx < total) {
    int k = idx & 255;
    int n = (idx >> 8) & 511;
    int h = idx >> 17;
    float w = (n < 256) ? igw[(h*BW + k)*BW + n]
                        : rgw[(h*BW + k)*BW + (n - 256)];
    wt[idx] = f2bf(w);
  }
  if (idx < D_) {
    float z = rp[idx];
    sp[idx] = fmaxf(z, 0.0f) + log1pf(__expf(-fabsf(z)));
  }
}

// ---------------- gates: block = 4 waves, each wave = 16 rows x 512 cols of one head,
// processed as 4 column-chunks of (64 ig | 64 rg) cols so only acc[8] (32 VGPRs) is
// live at a time. A-fragments (8 k-tiles, 32 VGPRs) are loaded once and reused across
// chunks. __launch_bounds__(256,4) caps regs at 128 -> 4 waves/SIMD (vs 1 before).
// MFMA 16x16x32 bf16. A-frag: A[m=lane&15][k=quad*8+j]; B-frag: B[k=quad*8+j][n=lane&15];
// C/D: col=lane&15, row=quad*4+r.
__global__ __launch_bounds__(256, 4) void gates_kernel(
    const float* __restrict__ act, const int* __restrict__ pos,
    const float* __restrict__ igb, const float* __restrict__ rgb,
    const unsigned short* __restrict__ wt, const float* __restrict__ sp,
    __half* __restrict__ la, __half* __restrict__ xn) {
  const int h    = blockIdx.y;
  const int wave = threadIdx.x >> 6;
  const int lane = threadIdx.x & 63;
  const int l15  = lane & 15;
  const int quad = lane >> 4;
  const int m0   = blockIdx.x * 64 + wave * 16;
  const int hd   = h * BW;

  // ---- load all A fragments (16 rows x 256 k, bf16) into registers
  const float* arow = act + (size_t)(m0 + l15) * D_ + hd;
  s16x8 A[8];
  #pragma unroll
  for (int kt = 0; kt < 8; ++kt) {
    const int koff = kt * 32 + quad * 8;
    f32x4 f0 = *(const f32x4*)(arow + koff);
    f32x4 f1 = *(const f32x4*)(arow + koff + 4);
    s16x8 af;
    af[0] = (short)f2bf(f0[0]); af[1] = (short)f2bf(f0[1]);
    af[2] = (short)f2bf(f0[2]); af[3] = (short)f2bf(f0[3]);
    af[4] = (short)f2bf(f1[0]); af[5] = (short)f2bf(f1[1]);
    af[6] = (short)f2bf(f1[2]); af[7] = (short)f2bf(f1[3]);
    A[kt] = af;
  }

  int  rowv[4];
  bool rst[4];
  #pragma unroll
  for (int r = 0; r < 4; ++r) {
    rowv[r] = m0 + quad * 4 + r;
    rst[r]  = (pos[rowv[r]] == 0);
  }

  const unsigned short* wth = wt + (size_t)h * 512 * 256;
  const unsigned short* wb  = wth + (size_t)l15 * 256;   // this lane's column base

  for (int g = 0; g < 4; ++g) {
    f32x4 acc[8];
    #pragma unroll
    for (int q = 0; q < 8; ++q) acc[q] = (f32x4){0.f, 0.f, 0.f, 0.f};

    #pragma unroll
    for (int kt = 0; kt < 8; ++kt) {
      const int ko = kt * 32 + quad * 8;
      #pragma unroll
      for (int q = 0; q < 4; ++q) {
        const s16x8 big = *(const s16x8*)(wb + (size_t)((g*64 + q*16)      ) * 256 + ko);
        const s16x8 brg = *(const s16x8*)(wb + (size_t)((g*64 + q*16) + 256) * 256 + ko);
        acc[q]     = __builtin_amdgcn_mfma_f32_16x16x32_bf16(A[kt], big, acc[q],     0, 0, 0);
        acc[q + 4] = __builtin_amdgcn_mfma_f32_16x16x32_bf16(A[kt], brg, acc[q + 4], 0, 0, 0);
      }
    }

    // epilogue for this 64-column chunk
    #pragma unroll
    for (int q = 0; q < 4; ++q) {
      const int j = g * 64 + q * 16 + l15;
      const int d = hd + j;
      const float bi  = igb[d];
      const float br  = rgb[d];
      const float spd = sp[d];
      #pragma unroll
      for (int r = 0; r < 4; ++r) {
        const int row = rowv[r];
        const float ig_logit = acc[q][r]     + bi;
        const float rg_logit = acc[q + 4][r] + br;
        const float igate = 1.0f / (1.0f + __expf(-ig_logit));
        const float rgate = 1.0f / (1.0f + __expf(-rg_logit));
        const float loga  = -8.0f * rgate * spd;
        const float a     = __expf(loga);
        const float mult  = rst[r] ? 1.0f : sqrtf(fmaxf(1.0f - a * a, 0.0f));
        const float xv    = act[(size_t)row * D_ + d];
        const float xo    = xv * igate * mult;
        const size_t o = (size_t)row * D_ + d;
        la[o] = __float2half(rst[r] ? -60000.0f : loga);
        xn[o] = __float2half(xo);
      }
    }
  }
}

// ---------------- scan phase A: per-chunk cumulative product + local scan
// 2 d-elements per thread: half2 loads, two independent fma chains, float2 stores.
__global__ __launch_bounds__(256) void scanA_kernel(
    const __half* __restrict__ la, const __half* __restrict__ xn,
    float* __restrict__ Pb, float* __restrict__ Xb) {
  const int d = (blockIdx.x * 256 + threadIdx.x) * 2;
  const int c = blockIdx.y;
  const int b = blockIdx.z;
  size_t base = ((size_t)b * T_ + (size_t)c * LCH) * D_ + d;
  float h0 = 0.f, h1 = 0.f, P0 = 1.f, P1 = 1.f;
  #pragma unroll 4
  for (int t = 0; t < LCH; ++t) {
    const __half2 lv = *(const __half2*)(la + base);
    const __half2 xv = *(const __half2*)(xn + base);
    const float2 lf = __half22float2(lv);
    const float2 xf = __half22float2(xv);
    const float a0 = __expf(lf.x);   // reset rows: -60000 -> 0
    const float a1 = __expf(lf.y);
    h0 = fmaf(a0, h0, xf.x);
    h1 = fmaf(a1, h1, xf.y);
    P0 *= a0;
    P1 *= a1;
    base += D_;
  }
  const size_t o = ((size_t)b * CCH + c) * D_ + d;
  *(float2*)(Pb + o) = make_float2(P0, P1);
  *(float2*)(Xb + o) = make_float2(h0, h1);
}

// ---------------- scan phase B: inter-chunk carry scan (tiny)
__global__ __launch_bounds__(256) void scanB_kernel(
    const float* __restrict__ Pb, const float* __restrict__ Xb,
    float* __restrict__ H0) {
  const int d = blockIdx.x * 256 + threadIdx.x;
  const int b = blockIdx.y;
  float carry = 0.f;
  for (int c = 0; c < CCH; ++c) {
    const size_t o = ((size_t)b * CCH + c) * D_ + d;
    H0[o] = carry;
    carry = fmaf(Pb[o], carry, Xb[o]);
  }
}

// ---------------- scan phase C: replay chunk with carry-in, write output (2-wide)
__global__ __launch_bounds__(256) void scanC_kernel(
    const __half* __restrict__ la, const __half* __restrict__ xn,
    const float* __restrict__ H0, float* __restrict__ out) {
  const int d = (blockIdx.x * 256 + threadIdx.x) * 2;
  const int c = blockIdx.y;
  const int b = blockIdx.z;
  size_t base = ((size_t)b * T_ + (size_t)c * LCH) * D_ + d;
  const size_t ho = ((size_t)b * CCH + c) * D_ + d;
  float h0 = H0[ho];
  float h1 = H0[ho + 1];
  #pragma unroll 4
  for (int t = 0; t < LCH; ++t) {
    const __half2 lv = *(const __half2*)(la + base);
    const __half2 xv = *(const __half2*)(xn + base);
    const float2 lf = __half22float2(lv);
    const float2 xf = __half22float2(xv);
    h0 = fmaf(__expf(lf.x), h0, xf.x);
    h1 = fmaf(__expf(lf.y), h1, xf.y);
    *(float2*)(out + base) = make_float2(h0, h1);
    base += D_;
  }
}

extern "C" void kernel_launch(void* const* d_in, const int* in_sizes, int n_in,
                              void* d_out, int out_size, void* d_ws, size_t ws_size,
                              hipStream_t stream) {
  const float* act = (const float*)d_in[0];
  const int*   pos = (const int*)d_in[1];
  const float* igw = (const float*)d_in[2];
  const float* igb = (const float*)d_in[3];
  const float* rgw = (const float*)d_in[4];
  const float* rgb = (const float*)d_in[5];
  const float* rp  = (const float*)d_in[6];
  float* out = (float*)d_out;

  char* ws = (char*)d_ws;
  __half* la = (__half*)ws;                 ws += (size_t)B_ * T_ * D_ * 2;
  __half* xn = (__half*)ws;                 ws += (size_t)B_ * T_ * D_ * 2;
  unsigned short* wt = (unsigned short*)ws; ws += (size_t)H_ * 512 * 256 * 2;
  float* sp = (float*)ws;                   ws += 4096;                      // D_*4 padded
  float* Pb = (float*)ws;                   ws += (size_t)B_ * CCH * D_ * 4;
  float* Xb = (float*)ws;                   ws += (size_t)B_ * CCH * D_ * 4;
  float* H0 = (float*)ws;                   ws += (size_t)B_ * CCH * D_ * 4;

  prep_kernel<<<dim3((H_ * 512 * 256 + 255) / 256), 256, 0, stream>>>(igw, rgw, rp, wt, sp);
  gates_kernel<<<dim3(NROWS / 64, H_), 256, 0, stream>>>(act, pos, igb, rgb, wt, sp, la, xn);
  scanA_kernel<<<dim3(D_ / 512, CCH, B_), 256, 0, stream>>>(la, xn, Pb, Xb);
  scanB_kernel<<<dim3(D_ / 256, B_), 256, 0, stream>>>(Pb, Xb, H0);
  scanC_kernel<<<dim3(D_ / 512, CCH, B_), 256, 0, stream>>>(la, xn, H0, out);
}

// Round 2
// 543.047 us; speedup vs baseline: 1.8840x; 1.3123x over previous
//
#include <hip/hip_runtime.h>
#include <hip/hip_fp16.h>
#include <cstdint>
#include <cstddef>

#define B_   4
#define T_   4096
#define D_   2560
#define H_   10
#define BW   256
#define NROWS (B_*T_)   // 16384
#define CCH  64         // number of chunks along T
#define LCH  64         // chunk length (CCH*LCH == T_)

typedef short s16x8 __attribute__((ext_vector_type(8)));
typedef float f32x4 __attribute__((ext_vector_type(4)));

__device__ __forceinline__ unsigned short f2bf(float f) {
  union { float f; uint32_t u; } v; v.f = f;
  uint32_t u = v.u;
  u += 0x7fffu + ((u >> 16) & 1u);   // round-to-nearest-even
  return (unsigned short)(u >> 16);
}

// async 16B global->LDS copy (per-lane global src, wave-uniform LDS base + lane*16)
__device__ __forceinline__ void async_copy16(const unsigned short* g, unsigned short* l) {
  __builtin_amdgcn_global_load_lds(
      (const __attribute__((address_space(1))) unsigned int*)g,
      (__attribute__((address_space(3))) unsigned int*)l,
      16, 0, 0);
}

// ---------------- prep: transpose+cast weights to bf16 [H][512][256] (n-major,
// k-contiguous, n<256 = ig cols, n>=256 = rg cols), and softplus(recurrent_param)
__global__ __launch_bounds__(256) void prep_kernel(
    const float* __restrict__ igw, const float* __restrict__ rgw,
    const float* __restrict__ rp,
    unsigned short* __restrict__ wt, float* __restrict__ sp) {
  int idx = blockIdx.x * 256 + threadIdx.x;
  const int total = H_ * 512 * 256;
  if (idx < total) {
    int k = idx & 255;
    int n = (idx >> 8) & 511;
    int h = idx >> 17;
    float w = (n < 256) ? igw[(h*BW + k)*BW + n]
                        : rgw[(h*BW + k)*BW + (n - 256)];
    wt[idx] = f2bf(w);
  }
  if (idx < D_) {
    float z = rp[idx];
    sp[idx] = fmaxf(z, 0.0f) + log1pf(__expf(-fabsf(z)));
  }
}

// Stage one 64KB B-chunk into LDS: chunk g covers ig cols [g*64,g*64+64) (lds n 0..63)
// and rg cols [256+g*64, +64) (lds n 64..127), full k=256, bf16, XOR-swizzled:
// lds[n*512 + (kb ^ ((n&7)<<4))] = w[n][kb]. Source address carries the inverse
// (same) XOR so global_load_lds's linear lane*16 write lands the right bytes.
__device__ __forceinline__ void stage_chunk(const unsigned short* __restrict__ wth,
                                            unsigned short* Bsm,
                                            int wave, int lane, int g) {
  #pragma unroll
  for (int i = 0; i < 16; ++i) {
    const int ob = wave * 16384 + i * 1024;   // wave-uniform LDS byte base (1KB/call)
    const int o  = ob + lane * 16;            // this lane's LDS byte slot
    const int n  = o >> 9;                    // 0..127
    const int nm = n + ((n < 64) ? g * 64 : 192 + g * 64);  // global weight col
    const int sb = (o & 511) ^ ((n & 7) << 4);              // swizzled k-byte
    async_copy16(wth + (size_t)nm * 256 + (sb >> 1), Bsm + (ob >> 1));
  }
}

// ---------------- gates: block = 4 waves x 32 rows = 128 rows, one head.
// B (weights) staged in LDS per 128-col chunk, shared by all 4 waves; each
// ds_read_b128 feeds 2 MFMAs (2 row-tiles). A register-resident across chunks.
// MFMA 16x16x32 bf16. A-frag: A[m=lane&15][k=quad*8+j]; B-frag: B[k=quad*8+j][n=lane&15];
// C/D: col=lane&15, row=quad*4+r.
__global__ __launch_bounds__(256, 2) void gates_kernel(
    const float* __restrict__ act, const int* __restrict__ pos,
    const float* __restrict__ igb, const float* __restrict__ rgb,
    const unsigned short* __restrict__ wt, const float* __restrict__ sp,
    __half* __restrict__ la, __half* __restrict__ xn) {
  __shared__ unsigned short Bsm[32768];   // 64 KB
  const int h    = blockIdx.y;
  const int wave = threadIdx.x >> 6;
  const int lane = threadIdx.x & 63;
  const int l15  = lane & 15;
  const int quad = lane >> 4;
  const int m0w  = blockIdx.x * 128 + wave * 32;
  const int hd   = h * BW;
  const unsigned short* wth = wt + (size_t)h * 512 * 256;

  // ---- A fragments: 2 row-tiles x 8 k-tiles (32 rows x 256 k), kept all kernel
  s16x8 A[2][8];
  #pragma unroll
  for (int mt = 0; mt < 2; ++mt) {
    const float* ar = act + (size_t)(m0w + mt * 16 + l15) * D_ + hd;
    #pragma unroll
    for (int kt = 0; kt < 8; ++kt) {
      const int ko = kt * 32 + quad * 8;
      f32x4 f0 = *(const f32x4*)(ar + ko);
      f32x4 f1 = *(const f32x4*)(ar + ko + 4);
      s16x8 af;
      af[0] = (short)f2bf(f0[0]); af[1] = (short)f2bf(f0[1]);
      af[2] = (short)f2bf(f0[2]); af[3] = (short)f2bf(f0[3]);
      af[4] = (short)f2bf(f1[0]); af[5] = (short)f2bf(f1[1]);
      af[6] = (short)f2bf(f1[2]); af[7] = (short)f2bf(f1[3]);
      A[mt][kt] = af;
    }
  }

  bool rst[2][4];
  #pragma unroll
  for (int mt = 0; mt < 2; ++mt)
    #pragma unroll
    for (int r = 0; r < 4; ++r)
      rst[mt][r] = (pos[m0w + mt * 16 + quad * 4 + r] == 0);

  stage_chunk(wth, Bsm, wave, lane, 0);

  for (int g = 0; g < 4; ++g) {
    __syncthreads();   // staging of chunk g complete (vmcnt drained + barrier)

    f32x4 acc[2][8];
    #pragma unroll
    for (int mt = 0; mt < 2; ++mt)
      #pragma unroll
      for (int nq = 0; nq < 8; ++nq)
        acc[mt][nq] = (f32x4){0.f, 0.f, 0.f, 0.f};

    #pragma unroll
    for (int kt = 0; kt < 8; ++kt) {
      #pragma unroll
      for (int nq = 0; nq < 8; ++nq) {
        const int bo = ((nq * 16 + l15) << 9) +
                       (((kt << 6) + (quad << 4)) ^ ((l15 & 7) << 4));
        const s16x8 bf = *(const s16x8*)((const char*)Bsm + bo);
        acc[0][nq] = __builtin_amdgcn_mfma_f32_16x16x32_bf16(A[0][kt], bf, acc[0][nq], 0, 0, 0);
        acc[1][nq] = __builtin_amdgcn_mfma_f32_16x16x32_bf16(A[1][kt], bf, acc[1][nq], 0, 0, 0);
      }
    }

    __syncthreads();   // all waves done reading chunk g
    if (g < 3) stage_chunk(wth, Bsm, wave, lane, g + 1);   // async prefetch

    // epilogue for this chunk overlaps the async staging above
    #pragma unroll
    for (int nqp = 0; nqp < 4; ++nqp) {
      const int d = hd + g * 64 + nqp * 16 + l15;
      const float bi  = igb[d];
      const float br  = rgb[d];
      const float spd = sp[d];
      #pragma unroll
      for (int mt = 0; mt < 2; ++mt) {
        #pragma unroll
        for (int r = 0; r < 4; ++r) {
          const int row = m0w + mt * 16 + quad * 4 + r;
          const float ig_logit = acc[mt][nqp][r]     + bi;
          const float rg_logit = acc[mt][nqp + 4][r] + br;
          const float igate = 1.0f / (1.0f + __expf(-ig_logit));
          const float rgate = 1.0f / (1.0f + __expf(-rg_logit));
          const float loga  = -8.0f * rgate * spd;
          const float a     = __expf(loga);
          const bool  rs    = rst[mt][r];
          const float mult  = rs ? 1.0f : sqrtf(fmaxf(1.0f - a * a, 0.0f));
          const float xv    = act[(size_t)row * D_ + d];
          const float xo    = xv * igate * mult;
          const size_t o = (size_t)row * D_ + d;
          la[o] = __float2half(rs ? -60000.0f : loga);
          xn[o] = __float2half(xo);
        }
      }
    }
  }
}

// ---------------- scan phase A: per-chunk cumulative product + local scan
// 2 d-elements per thread: half2 loads, two independent fma chains, float2 stores.
__global__ __launch_bounds__(256) void scanA_kernel(
    const __half* __restrict__ la, const __half* __restrict__ xn,
    float* __restrict__ Pb, float* __restrict__ Xb) {
  const int d = (blockIdx.x * 256 + threadIdx.x) * 2;
  const int c = blockIdx.y;
  const int b = blockIdx.z;
  size_t base = ((size_t)b * T_ + (size_t)c * LCH) * D_ + d;
  float h0 = 0.f, h1 = 0.f, P0 = 1.f, P1 = 1.f;
  #pragma unroll 4
  for (int t = 0; t < LCH; ++t) {
    const __half2 lv = *(const __half2*)(la + base);
    const __half2 xv = *(const __half2*)(xn + base);
    const float2 lf = __half22float2(lv);
    const float2 xf = __half22float2(xv);
    const float a0 = __expf(lf.x);   // reset rows: -60000 -> 0
    const float a1 = __expf(lf.y);
    h0 = fmaf(a0, h0, xf.x);
    h1 = fmaf(a1, h1, xf.y);
    P0 *= a0;
    P1 *= a1;
    base += D_;
  }
  const size_t o = ((size_t)b * CCH + c) * D_ + d;
  *(float2*)(Pb + o) = make_float2(P0, P1);
  *(float2*)(Xb + o) = make_float2(h0, h1);
}

// ---------------- scan phase B: inter-chunk carry scan, in-place (Pb becomes H0)
__global__ __launch_bounds__(256) void scanB_kernel(
    float* __restrict__ PbH, const float* __restrict__ Xb) {
  const int d = blockIdx.x * 256 + threadIdx.x;
  const int b = blockIdx.y;
  float carry = 0.f;
  for (int c = 0; c < CCH; ++c) {
    const size_t o = ((size_t)b * CCH + c) * D_ + d;
    const float P = PbH[o];
    PbH[o] = carry;            // H0 for chunk c
    carry = fmaf(P, carry, Xb[o]);
  }
}

// ---------------- scan phase C: replay chunk with carry-in, write output (2-wide)
__global__ __launch_bounds__(256) void scanC_kernel(
    const __half* __restrict__ la, const __half* __restrict__ xn,
    const float* __restrict__ H0, float* __restrict__ out) {
  const int d = (blockIdx.x * 256 + threadIdx.x) * 2;
  const int c = blockIdx.y;
  const int b = blockIdx.z;
  size_t base = ((size_t)b * T_ + (size_t)c * LCH) * D_ + d;
  const size_t ho = ((size_t)b * CCH + c) * D_ + d;
  float h0 = H0[ho];
  float h1 = H0[ho + 1];
  #pragma unroll 4
  for (int t = 0; t < LCH; ++t) {
    const __half2 lv = *(const __half2*)(la + base);
    const __half2 xv = *(const __half2*)(xn + base);
    const float2 lf = __half22float2(lv);
    const float2 xf = __half22float2(xv);
    h0 = fmaf(__expf(lf.x), h0, xf.x);
    h1 = fmaf(__expf(lf.y), h1, xf.y);
    *(float2*)(out + base) = make_float2(h0, h1);
    base += D_;
  }
}

extern "C" void kernel_launch(void* const* d_in, const int* in_sizes, int n_in,
                              void* d_out, int out_size, void* d_ws, size_t ws_size,
                              hipStream_t stream) {
  const float* act = (const float*)d_in[0];
  const int*   pos = (const int*)d_in[1];
  const float* igw = (const float*)d_in[2];
  const float* igb = (const float*)d_in[3];
  const float* rgw = (const float*)d_in[4];
  const float* rgb = (const float*)d_in[5];
  const float* rp  = (const float*)d_in[6];
  float* out = (float*)d_out;

  char* ws = (char*)d_ws;
  __half* la = (__half*)ws;                 ws += (size_t)B_ * T_ * D_ * 2;
  __half* xn = (__half*)ws;                 ws += (size_t)B_ * T_ * D_ * 2;
  unsigned short* wt = (unsigned short*)ws; ws += (size_t)H_ * 512 * 256 * 2;
  float* sp = (float*)ws;                   ws += 4096;                      // D_*4 padded
  float* Pb = (float*)ws;                   ws += (size_t)B_ * CCH * D_ * 4; // becomes H0
  float* Xb = (float*)ws;                   ws += (size_t)B_ * CCH * D_ * 4;

  prep_kernel<<<dim3((H_ * 512 * 256 + 255) / 256), 256, 0, stream>>>(igw, rgw, rp, wt, sp);
  gates_kernel<<<dim3(NROWS / 128, H_), 256, 0, stream>>>(act, pos, igb, rgb, wt, sp, la, xn);
  scanA_kernel<<<dim3(D_ / 512, CCH, B_), 256, 0, stream>>>(la, xn, Pb, Xb);
  scanB_kernel<<<dim3(D_ / 256, B_), 256, 0, stream>>>(Pb, Xb);
  scanC_kernel<<<dim3(D_ / 512, CCH, B_), 256, 0, stream>>>(la, xn, Pb, out);
}